// Round 12
// baseline (408.376 us; speedup 1.0000x reference)
//
#include <hip/hip_runtime.h>
#include <hip/hip_bf16.h>

// Problem constants
#define BDIM 8
#define TDIM 256
#define UDIM 64
#define HDIM 640
#define VDIM 1024
#define MDIM (BDIM * TDIM * UDIM)   // 131072

#define BK 32
#define NT (HDIM / BK)              // 20 K-tiles
#define NKC (HDIM / 8)              // 80 k-chunks per row
#define GSTRIDE (NKC * 128)         // 10240 ushort per 16-row group

typedef __attribute__((ext_vector_type(8))) short short8;   // 8 bf16 (16B)
typedef __attribute__((ext_vector_type(4))) float f32x4;

__device__ __forceinline__ ushort f2bf(float x) {
    union { float f; unsigned int u; } v; v.f = x;
    unsigned int r = (v.u + 0x7fffu + ((v.u >> 16) & 1u)) >> 16;  // RNE
    return (ushort)r;
}

// ---------------------------------------------------------------------------
// Fragment-tiled layout (verified r10/r11): element (row,k) lives at
//   chunk c = (row>>4)*80 + (k>>3); ushort idx = c*128 + (row&15)*8 + (k&7)
// One 16x32 MFMA fragment (group g, k-tile t) = contiguous 1KB at
// (g*80 + 4t)*128 = g*GSTRIDE + t*512, read as base + lane*16B.
// ---------------------------------------------------------------------------

// Prep 1: W (V x H fp32) -> fragment-tiled bf16. 81920 threads = 320 blocks.
__global__ __launch_bounds__(256) void cvt_w_tiled_kernel(
    const float* __restrict__ W, ushort* __restrict__ Wt)
{
    const int c  = blockIdx.x * 256 + threadIdx.x;
    const int lr = c & 15;
    const int q  = c >> 4;
    const int kc = q % NKC;
    const int g  = q / NKC;
    const int v  = g * 16 + lr;
    const float* src = W + (size_t)v * HDIM + kc * 8;
    f32x4 w0 = *(const f32x4*)src;
    f32x4 w1 = *(const f32x4*)(src + 4);
    short8 o;
    #pragma unroll
    for (int e = 0; e < 4; ++e) {
        o[e]     = (short)f2bf(w0[e]);
        o[e + 4] = (short)f2bf(w1[e]);
    }
    *(short8*)(Wt + (size_t)c * 8) = o;
}

// Prep 2: h = relu(f+p), fragment-tiled. 10,485,760 threads = 40960 blocks.
__global__ __launch_bounds__(256) void build_h_tiled_kernel(
    const float* __restrict__ f, const float* __restrict__ p,
    ushort* __restrict__ ht)
{
    const int c  = blockIdx.x * 256 + threadIdx.x;
    const int lr = c & 15;
    const int q  = c >> 4;
    const int kc = q % NKC;
    const int g  = q / NKC;
    const int m  = g * 16 + lr;
    const int b  = m >> 14;
    const int t  = (m >> 6) & (TDIM - 1);
    const int u  = m & (UDIM - 1);
    const int k  = kc * 8;
    const float* fr = f + (size_t)(b * TDIM + t) * HDIM + k;
    const float* pr = p + (size_t)(b * UDIM + u) * HDIM + k;
    f32x4 f0 = *(const f32x4*)fr;
    f32x4 f1 = *(const f32x4*)(fr + 4);
    f32x4 p0 = *(const f32x4*)pr;
    f32x4 p1 = *(const f32x4*)(pr + 4);
    short8 o;
    #pragma unroll
    for (int e = 0; e < 4; ++e) {
        float a0 = fmaxf(f0[e] + p0[e], 0.0f);
        float a1 = fmaxf(f1[e] + p1[e], 0.0f);
        o[e]     = (short)f2bf(a0);
        o[e + 4] = (short)f2bf(a1);
    }
    *(short8*)(ht + (size_t)c * 8) = o;
}

#define GLDS(srcptr, ldsptr)                                                   \
    __builtin_amdgcn_global_load_lds(                                          \
        (const __attribute__((address_space(1))) void*)(srcptr),               \
        (__attribute__((address_space(3))) void*)(ldsptr), 16, 0, 0)

// ============== LDS GEMM, fragment-tiled, 128x64 per-wave tile =============
// Block 256m x 128n, 4 waves (2x2), per-wave 128x64, acc 8x4. BK=32.
// Pipe budget per CU (2 blocks resident, per K-epoch):
//   MFMA: 2 waves/SIMD x 32 MFMA x 19.4 cyc = 1242 cyc (the target pipe)
//   TA:   2 blocks x 24KB, fully-contiguous 1KB wave-loads = 750 cyc (60%)
//   LDS:  8 waves x 12KB reads = 96KB /128B = 750 cyc (60%)
// -> both feeder pipes fit under the matrix pipe with headroom; 2
// independent blocks provide stall overlap (r6's proven +x lever).
// LDS: one buffer = 16 A-runs (1KB each) + 8 B-runs = 24KB; dbuf = 48KB.
// Staging: 24 x 1KB runs/tile; wave w issues runs w*6..w*6+5 (6 instr/wave)
// -> counted vmcnt(6), never 0 until the tail (r6 discipline, verified).
// Frag reads: lds base + lane*16B, contiguous 1KB -> 2 lanes/bank = free.
__global__ __launch_bounds__(256, 2) void hgemm_frag_kernel(
    const ushort* __restrict__ ht,    // fragment-tiled h
    const ushort* __restrict__ Wt,    // fragment-tiled W
    const float* __restrict__ bias,   // (V)
    float* __restrict__ out)          // (M,V) fp32
{
    __shared__ ushort Sh[2][12288];   // [dbuf][16 A-runs + 8 B-runs] 24KB each

    const int tid  = threadIdx.x;
    const int lane = tid & 63;
    const int wave = tid >> 6;   // 0..3
    const int wm   = wave >> 1;  // 0..1 -> 128-row half
    const int wn   = wave & 1;   // 0..1 -> 64-col half

    // Bijective XCD swizzle: 4096 blocks (%8==0). XCD x runs works
    // [x*512,(x+1)*512): 8 ntiles of one mtile consecutive -> A panel
    // (320KB) L2-reused 8x, Wt (1.25MB) L2-resident per XCD.
    const int bid   = blockIdx.x;
    const int work  = (bid & 7) * 512 + (bid >> 3);
    const int mtile = work >> 3;        // 0..511
    const int ntile = work & 7;         // 0..7
    const int m0 = mtile * 256;
    const int v0 = ntile * 128;

    const int gA0 = mtile * 16;         // 16 A groups
    const int gB0 = ntile * 8;          // 8 B groups
    const int la  = lane * 8;           // per-lane 16B within a run

    // Per-wave staging runs: q = wave*6 + i, i=0..5.
    // q<16: A group gA0+q -> Sh[bf][q*512]; q>=16: B group gB0+q-16 ->
    // Sh[bf][8192+(q-16)*512]. Source advances t*512 per K-tile.
    const ushort* sbase[6];
    int doff[6];
    #pragma unroll
    for (int i = 0; i < 6; ++i) {
        const int q = wave * 6 + i;
        if (q < 16) {
            sbase[i] = ht + (size_t)(gA0 + q) * GSTRIDE + la;
            doff[i]  = q * 512;
        } else {
            sbase[i] = Wt + (size_t)(gB0 + (q - 16)) * GSTRIDE + la;
            doff[i]  = 8192 + (q - 16) * 512;
        }
    }

    f32x4 acc[8][4];
    #pragma unroll
    for (int i = 0; i < 8; ++i)
        #pragma unroll
        for (int j = 0; j < 4; ++j)
            acc[i][j] = (f32x4)0.0f;

#define STG(kt, bf) do {                                                       \
        _Pragma("unroll")                                                      \
        for (int i_ = 0; i_ < 6; ++i_)                                         \
            GLDS(sbase[i_] + (kt) * 512, &Sh[bf][doff[i_]]);                   \
    } while (0)

#define TILE(t, d) do {                                                        \
        if ((t) + 1 < NT) {                                                    \
            STG((t) + 1, (d) ^ 1);                                             \
            asm volatile("s_waitcnt vmcnt(6)" ::: "memory");                   \
        } else {                                                               \
            asm volatile("s_waitcnt vmcnt(0)" ::: "memory");                   \
        }                                                                      \
        __builtin_amdgcn_sched_barrier(0);                                     \
        __builtin_amdgcn_s_barrier();       /* tile t landed for all waves */  \
        __builtin_amdgcn_sched_barrier(0);                                     \
        short8 afr[8], bfr[4];                                                 \
        _Pragma("unroll")                                                      \
        for (int mi = 0; mi < 8; ++mi)                                         \
            afr[mi] = *(const short8*)(&Sh[d][(wm * 8 + mi) * 512 + la]);      \
        _Pragma("unroll")                                                      \
        for (int ni = 0; ni < 4; ++ni)                                         \
            bfr[ni] = *(const short8*)(&Sh[d][8192 + (wn * 4 + ni) * 512 + la]);\
        __builtin_amdgcn_s_setprio(1);                                         \
        _Pragma("unroll")                                                      \
        for (int mi = 0; mi < 8; ++mi)                                         \
            _Pragma("unroll")                                                  \
            for (int ni = 0; ni < 4; ++ni)                                     \
                acc[mi][ni] = __builtin_amdgcn_mfma_f32_16x16x32_bf16(         \
                    afr[mi], bfr[ni], acc[mi][ni], 0, 0, 0);                   \
        __builtin_amdgcn_s_setprio(0);                                         \
        __builtin_amdgcn_sched_barrier(0);                                     \
        __builtin_amdgcn_s_barrier();       /* all done reading buf d */       \
    } while (0)

    STG(0, 0);
    #pragma unroll 1
    for (int t = 0; t < NT; t += 2) {
        TILE(t, 0);
        TILE(t + 1, 1);
    }
#undef TILE
#undef STG

    // Epilogue: C/D col = lane&15, row = (lane>>4)*4 + reg
    const int lr = lane & 15;
    #pragma unroll
    for (int ni = 0; ni < 4; ++ni) {
        const int col = v0 + wn * 64 + ni * 16 + lr;
        const float bv = bias[col];
        #pragma unroll
        for (int mi = 0; mi < 8; ++mi) {
            const int rbase = m0 + wm * 128 + mi * 16 + ((lane >> 4) << 2);
            #pragma unroll
            for (int reg = 0; reg < 4; ++reg) {
                out[(size_t)(rbase + reg) * VDIM + col] = acc[mi][ni][reg] + bv;
            }
        }
    }
}

// ---------------- fallback path (round-1 verified, linear layouts) ---------
__global__ void cvt_w_kernel(const float* __restrict__ W, ushort* __restrict__ Wb) {
    int i = (blockIdx.x * 256 + threadIdx.x) * 4;
    f32x4 w = *(const f32x4*)(W + i);
    ushort4 o;
    o.x = f2bf(w[0]); o.y = f2bf(w[1]); o.z = f2bf(w[2]); o.w = f2bf(w[3]);
    *(ushort4*)(Wb + i) = o;
}

template <bool USE_WB>
__global__ __launch_bounds__(256) void joint_gemm_kernel(
    const float* __restrict__ f, const float* __restrict__ p,
    const float* __restrict__ Wf, const ushort* __restrict__ Wb,
    const float* __restrict__ bias, float* __restrict__ out)
{
    __shared__ ushort Alds[128 * 64];
    __shared__ ushort Blds[128 * 64];

    const int tid  = threadIdx.x;
    const int lane = tid & 63;
    const int wave = tid >> 6;
    const int wm   = wave >> 1;
    const int wn   = wave & 1;

    const int bid   = blockIdx.x;
    const int work  = (bid & 7) * 1024 + (bid >> 3);
    const int mtile = work >> 3;
    const int ntile = work & 7;
    const int m0 = mtile * 128;
    const int v0 = ntile * 128;

    const int b  = m0 >> 14;
    const int t0 = (m0 >> 6) & (TDIM - 1);

    const float*  fbase = f + (size_t)(b * TDIM + t0) * HDIM;
    const float*  pbase = p + (size_t)b * UDIM * HDIM;
    const ushort* wbbase = Wb + (size_t)v0 * HDIM;
    const float*  wfbase = Wf + (size_t)v0 * HDIM;

    f32x4 acc[4][4];
    #pragma unroll
    for (int i = 0; i < 4; ++i)
        #pragma unroll
        for (int j = 0; j < 4; ++j)
            acc[i][j] = (f32x4)0.0f;

    for (int kt = 0; kt < HDIM / 64; ++kt) {
        const int k0 = kt * 64;
        __syncthreads();

        if (USE_WB) {
            #pragma unroll
            for (int it = 0; it < 4; ++it) {
                const int c   = it * 256 + tid;
                const int row = c >> 3;
                const int j   = c & 7;
                const ushort* src = wbbase + row * HDIM + k0 + ((j ^ (row & 7)) << 3);
                GLDS(src, &Blds[(it * 256 + wave * 64) * 8]);
            }
        } else {
            #pragma unroll
            for (int it = 0; it < 4; ++it) {
                const int c   = it * 256 + tid;
                const int row = c >> 3;
                const int j   = c & 7;
                const float* wp = wfbase + row * HDIM + k0 + j * 8;
                f32x4 w0 = *(const f32x4*)wp;
                f32x4 w1 = *(const f32x4*)(wp + 4);
                short8 wv;
                #pragma unroll
                for (int e = 0; e < 4; ++e) {
                    wv[e]     = (short)f2bf(w0[e]);
                    wv[e + 4] = (short)f2bf(w1[e]);
                }
                *(short8*)(&Blds[(row * 8 + (j ^ (row & 7))) * 8]) = wv;
            }
        }

        #pragma unroll
        for (int it = 0; it < 4; ++it) {
            const int c   = it * 256 + tid;
            const int row = c >> 3;
            const int j   = c & 7;
            const float* fp_ = fbase + (row >> 6) * HDIM + k0 + j * 8;
            const float* pp_ = pbase + (row & 63) * HDIM + k0 + j * 8;
            f32x4 f0 = *(const f32x4*)fp_;
            f32x4 f1 = *(const f32x4*)(fp_ + 4);
            f32x4 p0 = *(const f32x4*)pp_;
            f32x4 p1 = *(const f32x4*)(pp_ + 4);
            short8 hv;
            #pragma unroll
            for (int e = 0; e < 4; ++e) {
                float a0 = fmaxf(f0[e] + p0[e], 0.0f);
                float a1 = fmaxf(f1[e] + p1[e], 0.0f);
                hv[e]     = (short)f2bf(a0);
                hv[e + 4] = (short)f2bf(a1);
            }
            *(short8*)(&Alds[(row * 8 + (j ^ (row & 7))) * 8]) = hv;
        }

        __syncthreads();

        #pragma unroll
        for (int ks = 0; ks < 2; ++ks) {
            short8 afr[4], bfr[4];
            #pragma unroll
            for (int mi = 0; mi < 4; ++mi) {
                const int r = wm * 64 + mi * 16 + (lane & 15);
                const int j = ks * 4 + (lane >> 4);
                afr[mi] = *(const short8*)(&Alds[(r * 8 + (j ^ (r & 7))) * 8]);
            }
            #pragma unroll
            for (int ni = 0; ni < 4; ++ni) {
                const int r = wn * 64 + ni * 16 + (lane & 15);
                const int j = ks * 4 + (lane >> 4);
                bfr[ni] = *(const short8*)(&Blds[(r * 8 + (j ^ (r & 7))) * 8]);
            }
            #pragma unroll
            for (int mi = 0; mi < 4; ++mi)
                #pragma unroll
                for (int ni = 0; ni < 4; ++ni)
                    acc[mi][ni] = __builtin_amdgcn_mfma_f32_16x16x32_bf16(
                        afr[mi], bfr[ni], acc[mi][ni], 0, 0, 0);
        }
    }

    #pragma unroll
    for (int ni = 0; ni < 4; ++ni) {
        const int col = v0 + wn * 64 + ni * 16 + (lane & 15);
        const float bv = bias[col];
        #pragma unroll
        for (int mi = 0; mi < 4; ++mi) {
            const int rbase = m0 + wm * 64 + mi * 16 + ((lane >> 4) << 2);
            #pragma unroll
            for (int reg = 0; reg < 4; ++reg) {
                out[(size_t)(rbase + reg) * VDIM + col] = acc[mi][ni][reg] + bv;
            }
        }
    }
}

extern "C" void kernel_launch(void* const* d_in, const int* in_sizes, int n_in,
                              void* d_out, int out_size, void* d_ws, size_t ws_size,
                              hipStream_t stream) {
    const float* f    = (const float*)d_in[0];   // (8,256,640)
    const float* p    = (const float*)d_in[1];   // (8,64,640)
    const float* W    = (const float*)d_in[2];   // (1024,640)
    const float* bias = (const float*)d_in[3];   // (1024)
    float* out = (float*)d_out;                  // (8,256,64,1024) fp32

    const size_t wb_bytes = (size_t)VDIM * HDIM * sizeof(ushort);   // 1.25 MB
    const size_t h_bytes  = (size_t)MDIM * HDIM * sizeof(ushort);   // 160 MB

    if (ws_size >= wb_bytes + h_bytes) {
        ushort* Wt = (ushort*)d_ws;
        ushort* ht = (ushort*)((char*)d_ws + wb_bytes);
        cvt_w_tiled_kernel<<<(VDIM * HDIM / 8) / 256, 256, 0, stream>>>(W, Wt);
        build_h_tiled_kernel<<<(MDIM / 256) * (HDIM / 8), 256, 0, stream>>>(f, p, ht);
        const int grid = (MDIM / 256) * (VDIM / 128);   // 4096
        hgemm_frag_kernel<<<grid, 256, 0, stream>>>(ht, Wt, bias, out);
    } else if (ws_size >= wb_bytes) {
        ushort* Wb = (ushort*)d_ws;
        cvt_w_kernel<<<(VDIM * HDIM) / 1024, 256, 0, stream>>>(W, Wb);
        joint_gemm_kernel<true><<<(MDIM / 128) * (VDIM / 128), 256, 0, stream>>>(
            f, p, W, Wb, bias, out);
    } else {
        joint_gemm_kernel<false><<<(MDIM / 128) * (VDIM / 128), 256, 0, stream>>>(
            f, p, W, nullptr, bias, out);
    }
}

// Round 13
// 377.712 us; speedup vs baseline: 1.0812x; 1.0812x over previous
//
#include <hip/hip_runtime.h>
#include <hip/hip_bf16.h>

// Problem constants
#define BDIM 8
#define TDIM 256
#define UDIM 64
#define HDIM 640
#define VDIM 1024
#define MDIM (BDIM * TDIM * UDIM)   // 131072

#define BK 32
#define NT (HDIM / BK)              // 20 K-tiles

typedef __attribute__((ext_vector_type(8))) short short8;   // 8 bf16 (16B)
typedef __attribute__((ext_vector_type(4))) float f32x4;

__device__ __forceinline__ ushort f2bf(float x) {
    union { float f; unsigned int u; } v; v.f = x;
    unsigned int r = (v.u + 0x7fffu + ((v.u >> 16) & 1u)) >> 16;  // RNE
    return (ushort)r;
}

// Prep: W (V x H fp32) -> linear bf16 (B staging path needs linear rows).
__global__ void cvt_w_kernel(const float* __restrict__ W, ushort* __restrict__ Wb) {
    int i = (blockIdx.x * 256 + threadIdx.x) * 4;
    f32x4 w = *(const f32x4*)(W + i);
    ushort4 o;
    o.x = f2bf(w[0]); o.y = f2bf(w[1]); o.z = f2bf(w[2]); o.w = f2bf(w[3]);
    *(ushort4*)(Wb + i) = o;
}

#define GLDS(srcptr, ldsptr)                                                   \
    __builtin_amdgcn_global_load_lds(                                          \
        (const __attribute__((address_space(1))) void*)(srcptr),               \
        (__attribute__((address_space(3))) void*)(ldsptr), 16, 0, 0)

// ================== fused GEMM (r6 structure + in-loop A construct) ========
// 128x128 tile, BK=32, 4 waves (2x2), dbuf, 32KB LDS -> 4 blocks/CU (r6's
// best-measured config). A-tile h=relu(f+p) is constructed IN-LOOP into the
// spare LDS buffer (16 elems/thread/tile ~50 VALU cyc, co-issued under the
// MFMA shadow); B staged via r6's verified pre-swizzled global_load_lds.
// Kills build_h (35us) and the 160MB ht HBM round-trip.
//
// Sync audit (per tile t: vmcnt(0); BAR; ds_read bufs[d]; {construct A(t+1)
// + STG_B(t+1)} -> bufs[e]; MFMA; lgkmcnt(0); BAR):
//  - B(t) visible at BAR1: every wave ran vmcnt(0) (only B gloads can be
//    outstanding there - construct f/p loads were consumed+retired last
//    tile) BEFORE BAR1.  SAFE.
//  - A(t) visible at BAR1: constructed last tile; each wave flushed its
//    ds_writes with lgkmcnt(0) before last tile's END barrier.  SAFE.
//  - WAR on bufs[e]: all waves' reads of e-buffers (tile t-1) completed
//    before t-1's END barrier (frag regs consumed by MFMA before lgkm0).
//  - Construct f/p loads issued BEFORE the B gloads -> compiler's waits on
//    f/p (older) never force B to retire early; B stays in flight across
//    the barrier, landing ~1 phase later.
// Swizzle (verified r3/r4/r6, 0 conflicts): chunk slot = j ^ ((row>>1)&3);
// B: pre-swizzled global source; A: construct writes chunk j to slot.
__global__ __launch_bounds__(256, 4) void fused128_kernel(
    const float* __restrict__ f,      // (B,T,H) fp32
    const float* __restrict__ p,      // (B,U,H) fp32
    const ushort* __restrict__ Wb,    // (V,H) bf16 linear
    const float* __restrict__ bias,   // (V)
    float* __restrict__ out)          // (M,V) fp32
{
    __shared__ ushort Ash[2][128 * BK];  // 2 x 8 KB
    __shared__ ushort Bsh[2][128 * BK];  // 2 x 8 KB

    const int tid  = threadIdx.x;
    const int lane = tid & 63;
    const int wave = tid >> 6;   // 0..3
    const int wm   = wave >> 1;
    const int wn   = wave & 1;

    // Bijective XCD swizzle: 8192 blocks (%8==0); 8 ntiles of one mtile
    // consecutive per XCD -> f/p slices + Wb stay L2-hot.
    const int bid   = blockIdx.x;
    const int work  = (bid & 7) * 1024 + (bid >> 3);
    const int mtile = work >> 3;
    const int ntile = work & 7;
    const int m0 = mtile * 128;
    const int v0 = ntile * 128;

    const ushort* wbase = Wb + (size_t)v0 * HDIM;

    // ---- B staging map (r6 exact): 512 chunks/buf, 2 per thread ----
    const int r0a = tid >> 2;
    const int r0b = r0a + 64;
    const int j0  = tid & 3;
    const size_t sofB0 = (size_t)r0a * HDIM + (j0 ^ ((r0a >> 1) & 3)) * 8;
    const size_t sofB1 = (size_t)r0b * HDIM + (j0 ^ ((r0b >> 1) & 3)) * 8;
    const int u0 = (wave * 64) * 8;
    const int u1 = (256 + wave * 64) * 8;

    // ---- A construct map: 2 chunks/thread (i=0,1), chunk c=i*256+tid ----
    // row = c>>2 (m-row within tile), j = c&3 (k-chunk), slot = j^((row>>1)&3)
    int foffc[2], poffc[2], dstc[2];
    #pragma unroll
    for (int i = 0; i < 2; ++i) {
        const int c   = i * 256 + tid;
        const int row = c >> 2;
        const int j   = c & 3;
        const int m   = m0 + row;
        const int b   = m >> 14;
        const int t   = (m >> 6) & (TDIM - 1);
        const int u   = m & (UDIM - 1);
        foffc[i] = (b * TDIM + t) * HDIM + j * 8;
        poffc[i] = (b * UDIM + u) * HDIM + j * 8;
        dstc[i]  = (row * 4 + (j ^ ((row >> 1) & 3))) * 8;
    }

    // ---- fragment read offsets (r6 exact) ----
    int aoff[4], boff[4];
    #pragma unroll
    for (int mi = 0; mi < 4; ++mi) {
        const int r = wm * 64 + mi * 16 + (lane & 15);
        aoff[mi] = (r * 4 + ((lane >> 4) ^ ((r >> 1) & 3))) * 8;
    }
    #pragma unroll
    for (int ni = 0; ni < 4; ++ni) {
        const int r = wn * 64 + ni * 16 + (lane & 15);
        boff[ni] = (r * 4 + ((lane >> 4) ^ ((r >> 1) & 3))) * 8;
    }

    f32x4 acc[4][4];
    #pragma unroll
    for (int i = 0; i < 4; ++i)
        #pragma unroll
        for (int j = 0; j < 4; ++j)
            acc[i][j] = (f32x4)0.0f;

#define CONSTRUCT_A(kk, bf) do {                                               \
        _Pragma("unroll")                                                      \
        for (int i_ = 0; i_ < 2; ++i_) {                                       \
            const float* fp_ = f + foffc[i_] + (kk);                           \
            const float* pp_ = p + poffc[i_] + (kk);                           \
            f32x4 f0_ = *(const f32x4*)fp_;                                    \
            f32x4 f1_ = *(const f32x4*)(fp_ + 4);                              \
            f32x4 p0_ = *(const f32x4*)pp_;                                    \
            f32x4 p1_ = *(const f32x4*)(pp_ + 4);                              \
            short8 hv_;                                                        \
            _Pragma("unroll")                                                  \
            for (int e_ = 0; e_ < 4; ++e_) {                                   \
                float a0_ = fmaxf(f0_[e_] + p0_[e_], 0.0f);                    \
                float a1_ = fmaxf(f1_[e_] + p1_[e_], 0.0f);                    \
                hv_[e_]     = (short)f2bf(a0_);                                \
                hv_[e_ + 4] = (short)f2bf(a1_);                                \
            }                                                                  \
            *(short8*)(&Ash[bf][dstc[i_]]) = hv_;                              \
        }                                                                      \
    } while (0)

#define STG_B(kk, bf) do {                                                     \
        GLDS(wbase + sofB0 + (kk), &Bsh[bf][u0]);                              \
        GLDS(wbase + sofB1 + (kk), &Bsh[bf][u1]);                              \
    } while (0)

    // Prologue: tile 0 into buffers 0.
    CONSTRUCT_A(0, 0);
    STG_B(0, 0);
    asm volatile("s_waitcnt lgkmcnt(0)" ::: "memory");   // A(0) writes flushed

    int d = 0;
    #pragma unroll 1
    for (int t = 0; t < NT; ++t) {
        const int e = d ^ 1;
        // Only B gloads can be outstanding here (f/p consumed last tile).
        asm volatile("s_waitcnt vmcnt(0)" ::: "memory");
        __builtin_amdgcn_sched_barrier(0);
        __builtin_amdgcn_s_barrier();          // A(t), B(t) visible to all
        __builtin_amdgcn_sched_barrier(0);

        short8 afr[4], bfr[4];
        #pragma unroll
        for (int q = 0; q < 4; ++q) {
            afr[q] = *(const short8*)(&Ash[d][aoff[q]]);
            bfr[q] = *(const short8*)(&Bsh[d][boff[q]]);
        }

        if (t + 1 < NT) {
            const int kk = (t + 1) * BK;
            CONSTRUCT_A(kk, e);    // f/p loads first (older than B gloads)
            STG_B(kk, e);          // B stays in flight across the barrier
        }

        __builtin_amdgcn_s_setprio(1);
        #pragma unroll
        for (int mi = 0; mi < 4; ++mi)
            #pragma unroll
            for (int ni = 0; ni < 4; ++ni)
                acc[mi][ni] = __builtin_amdgcn_mfma_f32_16x16x32_bf16(
                    afr[mi], bfr[ni], acc[mi][ni], 0, 0, 0);
        __builtin_amdgcn_s_setprio(0);

        asm volatile("s_waitcnt lgkmcnt(0)" ::: "memory");  // frag reads +
        __builtin_amdgcn_sched_barrier(0);                  // A(t+1) writes
        __builtin_amdgcn_s_barrier();          // end: buf d reads retired
        d = e;
    }
#undef STG_B
#undef CONSTRUCT_A

    // Epilogue (r6 exact): C/D col = lane&15, row = (lane>>4)*4 + reg
    #pragma unroll
    for (int ni = 0; ni < 4; ++ni) {
        const int col = v0 + wn * 64 + ni * 16 + (lane & 15);
        const float bv = bias[col];
        #pragma unroll
        for (int mi = 0; mi < 4; ++mi) {
            const int rbase = m0 + wm * 64 + mi * 16 + ((lane >> 4) << 2);
            #pragma unroll
            for (int reg = 0; reg < 4; ++reg) {
                out[(size_t)(rbase + reg) * VDIM + col] = acc[mi][ni][reg] + bv;
            }
        }
    }
}

// ---------------- fallback (round-1 verified): fp32-W fused path -----------
template <bool USE_WB>
__global__ __launch_bounds__(256) void joint_gemm_kernel(
    const float* __restrict__ f, const float* __restrict__ p,
    const float* __restrict__ Wf, const ushort* __restrict__ Wb,
    const float* __restrict__ bias, float* __restrict__ out)
{
    __shared__ ushort Alds[128 * 64];
    __shared__ ushort Blds[128 * 64];

    const int tid  = threadIdx.x;
    const int lane = tid & 63;
    const int wave = tid >> 6;
    const int wm   = wave >> 1;
    const int wn   = wave & 1;

    const int bid   = blockIdx.x;
    const int work  = (bid & 7) * 1024 + (bid >> 3);
    const int mtile = work >> 3;
    const int ntile = work & 7;
    const int m0 = mtile * 128;
    const int v0 = ntile * 128;

    const int b  = m0 >> 14;
    const int t0 = (m0 >> 6) & (TDIM - 1);

    const float*  fbase = f + (size_t)(b * TDIM + t0) * HDIM;
    const float*  pbase = p + (size_t)b * UDIM * HDIM;
    const ushort* wbbase = Wb + (size_t)v0 * HDIM;
    const float*  wfbase = Wf + (size_t)v0 * HDIM;

    f32x4 acc[4][4];
    #pragma unroll
    for (int i = 0; i < 4; ++i)
        #pragma unroll
        for (int j = 0; j < 4; ++j)
            acc[i][j] = (f32x4)0.0f;

    for (int kt = 0; kt < HDIM / 64; ++kt) {
        const int k0 = kt * 64;
        __syncthreads();

        if (USE_WB) {
            #pragma unroll
            for (int it = 0; it < 4; ++it) {
                const int c   = it * 256 + tid;
                const int row = c >> 3;
                const int j   = c & 7;
                const ushort* src = wbbase + row * HDIM + k0 + ((j ^ (row & 7)) << 3);
                GLDS(src, &Blds[(it * 256 + wave * 64) * 8]);
            }
        } else {
            #pragma unroll
            for (int it = 0; it < 4; ++it) {
                const int c   = it * 256 + tid;
                const int row = c >> 3;
                const int j   = c & 7;
                const float* wp = wfbase + row * HDIM + k0 + j * 8;
                f32x4 w0 = *(const f32x4*)wp;
                f32x4 w1 = *(const f32x4*)(wp + 4);
                short8 wv;
                #pragma unroll
                for (int e = 0; e < 4; ++e) {
                    wv[e]     = (short)f2bf(w0[e]);
                    wv[e + 4] = (short)f2bf(w1[e]);
                }
                *(short8*)(&Blds[(row * 8 + (j ^ (row & 7))) * 8]) = wv;
            }
        }

        #pragma unroll
        for (int it = 0; it < 4; ++it) {
            const int c   = it * 256 + tid;
            const int row = c >> 3;
            const int j   = c & 7;
            const float* fp_ = fbase + (row >> 6) * HDIM + k0 + j * 8;
            const float* pp_ = pbase + (row & 63) * HDIM + k0 + j * 8;
            f32x4 f0 = *(const f32x4*)fp_;
            f32x4 f1 = *(const f32x4*)(fp_ + 4);
            f32x4 p0 = *(const f32x4*)pp_;
            f32x4 p1 = *(const f32x4*)(pp_ + 4);
            short8 hv;
            #pragma unroll
            for (int e = 0; e < 4; ++e) {
                float a0 = fmaxf(f0[e] + p0[e], 0.0f);
                float a1 = fmaxf(f1[e] + p1[e], 0.0f);
                hv[e]     = (short)f2bf(a0);
                hv[e + 4] = (short)f2bf(a1);
            }
            *(short8*)(&Alds[(row * 8 + (j ^ (row & 7))) * 8]) = hv;
        }

        __syncthreads();

        #pragma unroll
        for (int ks = 0; ks < 2; ++ks) {
            short8 afr[4], bfr[4];
            #pragma unroll
            for (int mi = 0; mi < 4; ++mi) {
                const int r = wm * 64 + mi * 16 + (lane & 15);
                const int j = ks * 4 + (lane >> 4);
                afr[mi] = *(const short8*)(&Alds[(r * 8 + (j ^ (r & 7))) * 8]);
            }
            #pragma unroll
            for (int ni = 0; ni < 4; ++ni) {
                const int r = wn * 64 + ni * 16 + (lane & 15);
                const int j = ks * 4 + (lane >> 4);
                bfr[ni] = *(const short8*)(&Blds[(r * 8 + (j ^ (r & 7))) * 8]);
            }
            #pragma unroll
            for (int mi = 0; mi < 4; ++mi)
                #pragma unroll
                for (int ni = 0; ni < 4; ++ni)
                    acc[mi][ni] = __builtin_amdgcn_mfma_f32_16x16x32_bf16(
                        afr[mi], bfr[ni], acc[mi][ni], 0, 0, 0);
        }
    }

    #pragma unroll
    for (int ni = 0; ni < 4; ++ni) {
        const int col = v0 + wn * 64 + ni * 16 + (lane & 15);
        const float bv = bias[col];
        #pragma unroll
        for (int mi = 0; mi < 4; ++mi) {
            const int rbase = m0 + wm * 64 + mi * 16 + ((lane >> 4) << 2);
            #pragma unroll
            for (int reg = 0; reg < 4; ++reg) {
                out[(size_t)(rbase + reg) * VDIM + col] = acc[mi][ni][reg] + bv;
            }
        }
    }
}

extern "C" void kernel_launch(void* const* d_in, const int* in_sizes, int n_in,
                              void* d_out, int out_size, void* d_ws, size_t ws_size,
                              hipStream_t stream) {
    const float* f    = (const float*)d_in[0];   // (8,256,640)
    const float* p    = (const float*)d_in[1];   // (8,64,640)
    const float* W    = (const float*)d_in[2];   // (1024,640)
    const float* bias = (const float*)d_in[3];   // (1024)
    float* out = (float*)d_out;                  // (8,256,64,1024) fp32

    const size_t wb_bytes = (size_t)VDIM * HDIM * sizeof(ushort);   // 1.25 MB
    const int grid = (MDIM / 128) * (VDIM / 128);  // 8192

    if (ws_size >= wb_bytes) {
        ushort* Wb = (ushort*)d_ws;
        cvt_w_kernel<<<(VDIM * HDIM) / 1024, 256, 0, stream>>>(W, Wb);
        fused128_kernel<<<grid, 256, 0, stream>>>(f, p, Wb, bias, out);
    } else {
        joint_gemm_kernel<false><<<grid, 256, 0, stream>>>(
            f, p, W, nullptr, bias, out);
    }
}